// Round 18
// baseline (96.557 us; speedup 1.0000x reference)
//
#include <hip/hip_runtime.h>
#include <hip/hip_bf16.h>
#include <stdint.h>

using bf16x8 = __attribute__((ext_vector_type(8))) __bf16;
using f32x4  = __attribute__((ext_vector_type(4))) float;
using i32x4  = __attribute__((ext_vector_type(4))) int;
using i32x2  = __attribute__((ext_vector_type(2))) int;

#define TM 128
#define TN 128
#define TK 128      // K-tile: A int8 16 KB, B 4-bit 8 KB
#define PROWS 8

__device__ __forceinline__ void gload_lds16(const void* g, void* l) {
  __builtin_amdgcn_global_load_lds((const __attribute__((address_space(1))) void*)g,
                                   (__attribute__((address_space(3))) void*)l,
                                   16, 0, 0);
}

__device__ __forceinline__ int pack4(int a, int b, int c, int d) {
  return (a & 0xFF) | ((b & 0xFF) << 8) | ((c & 0xFF) << 16) | ((d & 0xFF) << 24);
}

// ---- pack B: 4-bit nibbles, row-streaming (sequential 128B reads/lane/iter) ----
// wsB: [panel p][tile t (128 k)][row 0..127][4 slots x 16 B]  (row = 64 B)
// slot sl = (u ^ (row&3)) holds 32-k unit u; within 16 B, word w packs
// k w*8+b as lo-nibble and k w*8+b+4 as hi-nibble of byte b (expand-friendly).
__global__ __launch_bounds__(256)
void pack_rows_i4(const int* __restrict__ qw, uint8_t* __restrict__ wsB,
                  int K, int nT) {
  const int tid = threadIdx.x;
  const int rloc = tid >> 5;                  // 0..7
  const int lane32 = tid & 31;
  const int n = blockIdx.x * PROWS + rloc;
  const int p = n >> 7;
  const int rit = n & 127;
  const int rb3 = rit & 3;
  const int* qrow = qw + (size_t)n * K;
  uint8_t* base = wsB + (size_t)p * nT * 8192 + rit * 64;

#pragma unroll
  for (int j = 0; j < 4; ++j) {
    const int cu = lane32 + j * 32;           // 32-k unit 0..127
    const i32x4* s4 = reinterpret_cast<const i32x4*>(qrow + cu * 32);
    i32x4 qv[8];
#pragma unroll
    for (int e = 0; e < 8; ++e) qv[e] = s4[e];
    i32x4 w;
#pragma unroll
    for (int wj = 0; wj < 4; ++wj) {
      int v = 0;
#pragma unroll
      for (int b = 0; b < 4; ++b)
        v |= ((qv[2 * wj][b] & 0xF) | ((qv[2 * wj + 1][b] & 0xF) << 4)) << (8 * b);
      w[wj] = v;
    }
    const int t  = cu >> 2;                   // 4 units per 128-k tile
    const int sl = (cu & 3) ^ rb3;
    *reinterpret_cast<i32x4*>(base + (size_t)t * 8192 + sl * 16) = w;
  }
}

// ---- pack A: x fp32 -> int8 (scale 1/16), R17-proven layout ----
__global__ __launch_bounds__(256)
void xcvt_i8(const float* __restrict__ x, int8_t* __restrict__ wsA, int K, int nT) {
  const int U  = blockIdx.x * 256 + threadIdx.x;
  const int uu = U & 1023;
  const int tt = (U >> 10) % nT;
  const int bb = (U >> 10) / nT;              // 128-row band
  const int row = uu >> 3, sl = uu & 7;
  const int c16 = sl ^ (row & 7);
  const f32x4* src = reinterpret_cast<const f32x4*>(
      x + (size_t)(bb * 128 + row) * K + tt * TK + c16 * 16);
  f32x4 v0 = src[0], v1 = src[1], v2 = src[2], v3 = src[3];
  int q[16];
#pragma unroll
  for (int e = 0; e < 4; ++e) {
    q[e]      = __float2int_rn(v0[e] * 16.f);
    q[4 + e]  = __float2int_rn(v1[e] * 16.f);
    q[8 + e]  = __float2int_rn(v2[e] * 16.f);
    q[12 + e] = __float2int_rn(v3[e] * 16.f);
  }
#pragma unroll
  for (int e = 0; e < 16; ++e) q[e] = q[e] > 127 ? 127 : (q[e] < -127 ? -127 : q[e]);
  i32x4 w;
  w[0] = pack4(q[0], q[1], q[2], q[3]);
  w[1] = pack4(q[4], q[5], q[6], q[7]);
  w[2] = pack4(q[8], q[9], q[10], q[11]);
  w[3] = pack4(q[12], q[13], q[14], q[15]);
  *reinterpret_cast<i32x4*>(wsA + (size_t)U * 16) = w;
}

// ---- int8 x 4-bit GEMM: R17 step engine, B expanded from nibbles ----
__global__ __launch_bounds__(256, 2)
void gemm_i8(const int8_t* __restrict__ wsA, const uint8_t* __restrict__ wsB,
             const float* __restrict__ scales, const float* __restrict__ bias,
             float* __restrict__ out, int N, int K, int NG, int gy) {
  __shared__ int8_t  As[2][16384];            // 2 x 16 KiB
  __shared__ uint8_t Bs[2][8192];             // 2 x 8 KiB (4-bit)
  __shared__ float   sS[32 * 128];            // 16 KiB: [g][col], x-scale folded

  const int tid  = threadIdx.x;
  const int lane = tid & 63;
  const int wv   = tid >> 6;                  // 0..3
  const int wr   = wv >> 1;                   // 0..1 (M)
  const int wc   = wv & 1;                    // 0..1 (N)
  const int l15  = lane & 15;
  const int l4   = lane >> 4;

  // XCD chunk (344 = 8*43 exact), by-innermost
  int wgid = blockIdx.x;
  if ((gridDim.x & 7) == 0) {
    const int q = gridDim.x >> 3;
    wgid = (blockIdx.x & 7) * q + (blockIdx.x >> 3);
  }
  const int bx = wgid / gy;
  const int by = wgid % gy;
  const int tileM = by * TM;
  const int tileN = bx * TN;
  const int nT = K / TK;                      // 32 (== NG)

  for (int idx = tid; idx < NG * 128; idx += 256) {
    const int g = idx >> 7, col = idx & 127;
    sS[g * 128 + col] = scales[(size_t)(tileN + col) * NG + g] * 0.0625f;
  }
  __syncthreads();                            // full drain: clean vmcnt queue

  const int8_t*  srcA = wsA + (size_t)by * nT * 16384;
  const uint8_t* srcB = wsB + (size_t)bx * nT * 8192;

  i32x4 acc[4][4];
  f32x4 accf[4][4];
#pragma unroll
  for (int m = 0; m < 4; ++m)
#pragma unroll
    for (int n = 0; n < 4; ++n) { acc[m][n] = (i32x4)0; accf[m][n] = (f32x4)0.0f; }

  // 6 gload_lds16 per thread per stage (A 4 + B 2)
  auto STAGE = [&](int buf, int t) {
    const int8_t*  a = srcA + (size_t)t * 16384;
    const uint8_t* b = srcB + (size_t)t * 8192;
#pragma unroll
    for (int i = 0; i < 4; ++i) {
      const int ub = i * 256 + wv * 64;
      gload_lds16(a + (size_t)(ub + lane) * 16, &As[buf][ub * 16]);
    }
#pragma unroll
    for (int i = 0; i < 2; ++i) {
      const int ub = i * 256 + wv * 64;       // 512 units of 16 B
      gload_lds16(b + (size_t)(ub + lane) * 16, &Bs[buf][ub * 16]);
    }
  };

  STAGE(0, 0);
  STAGE(1, 1);                                // 12 outstanding per thread

  for (int t = 0; t < nT; ++t) {
    if (t + 1 < nT) { asm volatile("s_waitcnt vmcnt(6)" ::: "memory"); }
    else            { asm volatile("s_waitcnt vmcnt(0)" ::: "memory"); }
    __builtin_amdgcn_s_barrier();
    __builtin_amdgcn_sched_barrier(0);

    const int cur = t & 1;
#pragma unroll
    for (int kk = 0; kk < 2; ++kk) {          // two K=64 MFMAs per 128-k tile
      const int c16 = kk * 4 + l4;
      i32x4 af[4], bf[4];
#pragma unroll
      for (int m = 0; m < 4; ++m) {
        const int row = wr * 64 + m * 16 + l15;
        const int sl = c16 ^ (row & 7);
        af[m] = *reinterpret_cast<const i32x4*>(&As[cur][row * 128 + sl * 16]);
      }
#pragma unroll
      for (int n = 0; n < 4; ++n) {
        const int col = wc * 64 + n * 16 + l15;
        const int u = c16 >> 1, h = c16 & 1;
        const int sl = u ^ (col & 3);
        i32x2 pw = *reinterpret_cast<const i32x2*>(&Bs[cur][col * 64 + sl * 16 + h * 8]);
        bf[n][0] = pw[0] & 0x0F0F0F0F;
        bf[n][1] = (pw[0] >> 4) & 0x0F0F0F0F;
        bf[n][2] = pw[1] & 0x0F0F0F0F;
        bf[n][3] = (pw[1] >> 4) & 0x0F0F0F0F;
      }
#pragma unroll
      for (int m = 0; m < 4; ++m)
#pragma unroll
        for (int n = 0; n < 4; ++n)
          acc[m][n] = __builtin_amdgcn_mfma_i32_16x16x64_i8(af[m], bf[n], acc[m][n], 0, 0, 0);
    }

    __builtin_amdgcn_sched_barrier(0);
    __builtin_amdgcn_s_barrier();             // buf cur consumed by all waves
    if (t + 2 < nT) STAGE(cur, t + 2);

    // group close (g == t, GS == TK): accf += s[col] * float(acc); acc = 0
    float s[4];
#pragma unroll
    for (int n = 0; n < 4; ++n)
      s[n] = sS[t * 128 + wc * 64 + n * 16 + l15];
#pragma unroll
    for (int m = 0; m < 4; ++m)
#pragma unroll
      for (int n = 0; n < 4; ++n) {
        accf[m][n] += s[n] * __builtin_convertvector(acc[m][n], f32x4);
        acc[m][n] = (i32x4)0;
      }
    __builtin_amdgcn_sched_barrier(0);
  }

  // epilogue: D row = l4*4 + r, col = l15 (verified, dtype-independent)
#pragma unroll
  for (int n = 0; n < 4; ++n) {
    const int col = tileN + wc * 64 + n * 16 + l15;
    const float bv = bias[col];
#pragma unroll
    for (int m = 0; m < 4; ++m) {
      const int rbase = tileM + wr * 64 + m * 16 + l4 * 4;
#pragma unroll
      for (int r = 0; r < 4; ++r)
        out[(size_t)(rbase + r) * N + col] = accf[m][n][r] + bv;
    }
  }
}

// ======================= last-resort fallback (no ws) =======================
#define FBM 128
#define FBN 128
#define FBK 64
__global__ __launch_bounds__(256)
void gptq_gemm_fb(const float* __restrict__ x, const int* __restrict__ qw,
                  const float* __restrict__ scales, const float* __restrict__ bias,
                  float* __restrict__ out, int M, int N, int K, int NG, int GS) {
  __shared__ __bf16 lds_a[FBM * FBK];
  __shared__ __bf16 lds_b[FBN * FBK];
  const int tid = threadIdx.x, lane = tid & 63, wave = tid >> 6;
  const int wr = wave >> 1, wc = wave & 1;
  const int tileM = blockIdx.y * FBM, tileN = blockIdx.x * FBN;
  const int l15 = lane & 15, l4 = lane >> 4;
  f32x4 acc[4][4];
#pragma unroll
  for (int m = 0; m < 4; ++m)
#pragma unroll
    for (int n = 0; n < 4; ++n) acc[m][n] = (f32x4)0.0f;
  for (int k0 = 0; k0 < K; k0 += FBK) {
    const int g = k0 / GS;
#pragma unroll
    for (int i = 0; i < 4; ++i) {
      int u = i * 256 + tid, row = u >> 3, c8 = u & 7;
      const f32x4* src = reinterpret_cast<const f32x4*>(x + (size_t)(tileM + row) * K + k0 + c8 * 8);
      f32x4 v0 = src[0], v1 = src[1];
      bf16x8 w;
      w[0]=(__bf16)v0[0]; w[1]=(__bf16)v0[1]; w[2]=(__bf16)v0[2]; w[3]=(__bf16)v0[3];
      w[4]=(__bf16)v1[0]; w[5]=(__bf16)v1[1]; w[6]=(__bf16)v1[2]; w[7]=(__bf16)v1[3];
      int slot = c8 ^ (row & 7);
      *reinterpret_cast<bf16x8*>(&lds_a[row * FBK + slot * 8]) = w;
    }
#pragma unroll
    for (int i = 0; i < 4; ++i) {
      int u = i * 256 + tid, row = u >> 3, c8 = u & 7;
      int gn = tileN + row;
      const i32x4* src = reinterpret_cast<const i32x4*>(qw + (size_t)gn * K + k0 + c8 * 8);
      i32x4 q0 = src[0], q1 = src[1];
      float s = scales[gn * NG + g];
      bf16x8 w;
      w[0]=(__bf16)((float)q0[0]*s); w[1]=(__bf16)((float)q0[1]*s);
      w[2]=(__bf16)((float)q0[2]*s); w[3]=(__bf16)((float)q0[3]*s);
      w[4]=(__bf16)((float)q1[0]*s); w[5]=(__bf16)((float)q1[1]*s);
      w[6]=(__bf16)((float)q1[2]*s); w[7]=(__bf16)((float)q1[3]*s);
      int slot = c8 ^ (row & 7);
      *reinterpret_cast<bf16x8*>(&lds_b[row * FBK + slot * 8]) = w;
    }
    __syncthreads();
#pragma unroll
    for (int kk = 0; kk < FBK; kk += 32) {
      bf16x8 af[4], bfr[4];
#pragma unroll
      for (int m = 0; m < 4; ++m) {
        int row = wr * 64 + m * 16 + l15, slot = ((kk >> 3) + l4) ^ (row & 7);
        af[m] = *reinterpret_cast<const bf16x8*>(&lds_a[row * FBK + slot * 8]);
      }
#pragma unroll
      for (int n = 0; n < 4; ++n) {
        int row = wc * 64 + n * 16 + l15, slot = ((kk >> 3) + l4) ^ (row & 7);
        bfr[n] = *reinterpret_cast<const bf16x8*>(&lds_b[row * FBK + slot * 8]);
      }
#pragma unroll
      for (int m = 0; m < 4; ++m)
#pragma unroll
        for (int n = 0; n < 4; ++n)
          acc[m][n] = __builtin_amdgcn_mfma_f32_16x16x32_bf16(af[m], bfr[n], acc[m][n], 0, 0, 0);
    }
    __syncthreads();
  }
#pragma unroll
  for (int n = 0; n < 4; ++n) {
    int coln = tileN + wc * 64 + n * 16 + l15;
    float bv = bias[coln];
#pragma unroll
    for (int m = 0; m < 4; ++m) {
      int rbase = tileM + wr * 64 + m * 16 + l4 * 4;
#pragma unroll
      for (int r = 0; r < 4; ++r)
        out[(size_t)(rbase + r) * N + coln] = acc[m][n][r] + bv;
    }
  }
}

extern "C" void kernel_launch(void* const* d_in, const int* in_sizes, int n_in,
                              void* d_out, int out_size, void* d_ws, size_t ws_size,
                              hipStream_t stream) {
  const float* x      = (const float*)d_in[0];
  const int*   qw     = (const int*)d_in[1];
  const float* scales = (const float*)d_in[2];
  const float* bias   = (const float*)d_in[3];
  float*       out    = (float*)d_out;

  const int OUT = in_sizes[3];            // 11008
  const int IN  = in_sizes[1] / OUT;      // 4096
  const int M   = in_sizes[0] / IN;       // 512
  const int NG  = in_sizes[2] / OUT;      // 32
  const int GS  = IN / NG;                // 128

  const size_t needB = (size_t)OUT * IN / 2;          // 22.5 MB 4-bit
  const size_t needA = (size_t)M * IN;                // 2.1 MB int8
  const int nT = IN / TK;                             // 32

  const bool ok_i4 =
      (ws_size >= needB + needA) && (M % TM == 0) && (OUT % TN == 0) &&
      (IN % TK == 0) && (GS == TK) && (NG == nT) && (NG <= 32) && (nT >= 4) &&
      (OUT % PROWS == 0) && (IN % 32 == 0);

  if (ok_i4) {
    uint8_t* wsB = (uint8_t*)d_ws;
    int8_t*  wsA = (int8_t*)d_ws + needB;
    pack_rows_i4<<<OUT / PROWS, 256, 0, stream>>>(qw, wsB, IN, nT);
    const int bands = M / 128;            // 4
    const int unitsA = bands * nT * 1024;
    xcvt_i8<<<unitsA / 256, 256, 0, stream>>>(x, wsA, IN, nT);
    const int gx = OUT / TN;              // 86
    const int gy = M / TM;                // 4
    gemm_i8<<<gx * gy, 256, 0, stream>>>(wsA, wsB, scales, bias, out, OUT, IN, NG, gy);
  } else {
    dim3 grid(OUT / FBN, M / FBM);
    gptq_gemm_fb<<<grid, 256, 0, stream>>>(x, qw, scales, bias, out, M, OUT, IN, NG, GS);
  }
}

// Round 19
// 85.892 us; speedup vs baseline: 1.1242x; 1.1242x over previous
//
#include <hip/hip_runtime.h>
#include <hip/hip_bf16.h>
#include <stdint.h>

using bf16x8 = __attribute__((ext_vector_type(8))) __bf16;
using f32x4  = __attribute__((ext_vector_type(4))) float;
using i32x4  = __attribute__((ext_vector_type(4))) int;

#define TM 128
#define TN 128
#define TK 128      // int8 K-tile: 128 rows x 128 k x 1B = 16 KB per operand
#define PROWS 8

__device__ __forceinline__ void gload_lds16(const void* g, void* l) {
  __builtin_amdgcn_global_load_lds((const __attribute__((address_space(1))) void*)g,
                                   (__attribute__((address_space(3))) void*)l,
                                   16, 0, 0);
}

__device__ __forceinline__ int pack4(int a, int b, int c, int d) {
  return (a & 0xFF) | ((b & 0xFF) << 8) | ((c & 0xFF) << 16) | ((d & 0xFF) << 24);
}

// ---- fused prepass: blocks [0, nbB) pack B int8; blocks [nbB, nbB+nbA) pack A ----
// B: wsB[panel p][tile t][row][slot sl] ; sl holds q[row][(sl^(row&7))*16 + t*128 ..+16]
// A: x fp32 -> int8 (scale 1/16), same swizzled layout (R17-proven, byte-identical)
__global__ __launch_bounds__(256)
void prepass_i8(const int* __restrict__ qw, const float* __restrict__ x,
                int8_t* __restrict__ wsB, int8_t* __restrict__ wsA,
                int K, int nT, int nbB) {
  const int tid = threadIdx.x;
  if ((int)blockIdx.x < nbB) {
    // ---------------- pack B (R17 pack_rows_i8, byte-identical) ----------------
    const int rloc = tid >> 5;                  // 0..7
    const int lane32 = tid & 31;
    const int n = blockIdx.x * PROWS + rloc;
    const int p = n >> 7;
    const int rit = n & 127;
    const int rb7 = rit & 7;
    const int* qrow = qw + (size_t)n * K;
    int8_t* base = wsB + (size_t)p * nT * 16384 + rit * 128;

#pragma unroll
    for (int j = 0; j < 8; ++j) {
      const int cu = lane32 + j * 32;           // 16-elem k-unit 0..255
      const i32x4* s4 = reinterpret_cast<const i32x4*>(qrow + cu * 16);
      i32x4 q0 = s4[0], q1 = s4[1], q2 = s4[2], q3 = s4[3];
      const int t  = cu >> 3;                   // 8 units per 128-k tile
      const int sl = (cu & 7) ^ rb7;
      i32x4 w;
      w[0] = pack4(q0[0], q0[1], q0[2], q0[3]);
      w[1] = pack4(q1[0], q1[1], q1[2], q1[3]);
      w[2] = pack4(q2[0], q2[1], q2[2], q2[3]);
      w[3] = pack4(q3[0], q3[1], q3[2], q3[3]);
      *reinterpret_cast<i32x4*>(base + (size_t)t * 16384 + sl * 16) = w;
    }
  } else {
    // ---------------- pack A (R17 xcvt_i8, byte-identical) ----------------
    const int U  = ((int)blockIdx.x - nbB) * 256 + tid;
    const int uu = U & 1023;
    const int tt = (U >> 10) % nT;
    const int bb = (U >> 10) / nT;              // 128-row band
    const int row = uu >> 3, sl = uu & 7;
    const int c16 = sl ^ (row & 7);
    const f32x4* src = reinterpret_cast<const f32x4*>(
        x + (size_t)(bb * 128 + row) * K + tt * TK + c16 * 16);
    f32x4 v0 = src[0], v1 = src[1], v2 = src[2], v3 = src[3];
    int q[16];
#pragma unroll
    for (int e = 0; e < 4; ++e) {
      q[e]      = __float2int_rn(v0[e] * 16.f);
      q[4 + e]  = __float2int_rn(v1[e] * 16.f);
      q[8 + e]  = __float2int_rn(v2[e] * 16.f);
      q[12 + e] = __float2int_rn(v3[e] * 16.f);
    }
#pragma unroll
    for (int e = 0; e < 16; ++e) q[e] = q[e] > 127 ? 127 : (q[e] < -127 ? -127 : q[e]);
    i32x4 w;
    w[0] = pack4(q[0], q[1], q[2], q[3]);
    w[1] = pack4(q[4], q[5], q[6], q[7]);
    w[2] = pack4(q[8], q[9], q[10], q[11]);
    w[3] = pack4(q[12], q[13], q[14], q[15]);
    *reinterpret_cast<i32x4*>(wsA + (size_t)U * 16) = w;
  }
}

// ---- int8 GEMM: R17 step engine (128^2, 4 waves 2x2, vmcnt(8) 2-deep) ----
__global__ __launch_bounds__(256, 2)
void gemm_i8(const int8_t* __restrict__ wsA, const int8_t* __restrict__ wsB,
             const float* __restrict__ scales, const float* __restrict__ bias,
             float* __restrict__ out, int N, int K, int NG, int gy) {
  __shared__ int8_t As[2][16384];             // 2 x 16 KiB
  __shared__ int8_t Bs[2][16384];             // 2 x 16 KiB
  __shared__ float  sS[32 * 128];             // 16 KiB: [g][col], pre-scaled 1/16

  const int tid  = threadIdx.x;
  const int lane = tid & 63;
  const int wv   = tid >> 6;                  // 0..3
  const int wr   = wv >> 1;                   // 0..1 (M)
  const int wc   = wv & 1;                    // 0..1 (N)
  const int l15  = lane & 15;
  const int l4   = lane >> 4;

  // XCD chunk (344 = 8*43 exact), by-innermost: A-band sharers on one XCD
  int wgid = blockIdx.x;
  if ((gridDim.x & 7) == 0) {
    const int q = gridDim.x >> 3;
    wgid = (blockIdx.x & 7) * q + (blockIdx.x >> 3);
  }
  const int bx = wgid / gy;
  const int by = wgid % gy;
  const int tileM = by * TM;
  const int tileN = bx * TN;
  const int nT = K / TK;                      // 32 (== NG, since GS == TK)

  // preload scale panel transposed [g][col], folded x-scale 1/16
  for (int idx = tid; idx < NG * 128; idx += 256) {
    const int g = idx >> 7, col = idx & 127;
    sS[g * 128 + col] = scales[(size_t)(tileN + col) * NG + g] * 0.0625f;
  }
  __syncthreads();                            // drains vmcnt: clean queue

  const int8_t* srcA = wsA + (size_t)by * nT * 16384;
  const int8_t* srcB = wsB + (size_t)bx * nT * 16384;

  i32x4 acc[4][4];
  f32x4 accf[4][4];
#pragma unroll
  for (int m = 0; m < 4; ++m)
#pragma unroll
    for (int n = 0; n < 4; ++n) { acc[m][n] = (i32x4)0; accf[m][n] = (f32x4)0.0f; }

  // 8 gload_lds16 per thread per stage (A 4 + B 4); 16 KB each operand
  auto STAGE = [&](int buf, int t) {
    const int8_t* a = srcA + (size_t)t * 16384;
    const int8_t* b = srcB + (size_t)t * 16384;
#pragma unroll
    for (int i = 0; i < 4; ++i) {
      const int ub = i * 256 + wv * 64;       // uniform unit base; +lane per lane
      gload_lds16(a + (size_t)(ub + lane) * 16, &As[buf][ub * 16]);
      gload_lds16(b + (size_t)(ub + lane) * 16, &Bs[buf][ub * 16]);
    }
  };

  STAGE(0, 0);
  STAGE(1, 1);                                // 16 outstanding per thread

  for (int t = 0; t < nT; ++t) {
    if (t + 1 < nT) { asm volatile("s_waitcnt vmcnt(8)" ::: "memory"); }
    else            { asm volatile("s_waitcnt vmcnt(0)" ::: "memory"); }
    __builtin_amdgcn_s_barrier();
    __builtin_amdgcn_sched_barrier(0);

    const int cur = t & 1;
#pragma unroll
    for (int kk = 0; kk < 2; ++kk) {          // two K=64 MFMAs per 128-k tile
      const int c16 = kk * 4 + l4;
      i32x4 af[4], bf[4];
#pragma unroll
      for (int m = 0; m < 4; ++m) {
        const int row = wr * 64 + m * 16 + l15;
        const int sl = c16 ^ (row & 7);
        af[m] = *reinterpret_cast<const i32x4*>(&As[cur][row * 128 + sl * 16]);
      }
#pragma unroll
      for (int n = 0; n < 4; ++n) {
        const int col = wc * 64 + n * 16 + l15;
        const int sl = c16 ^ (col & 7);
        bf[n] = *reinterpret_cast<const i32x4*>(&Bs[cur][col * 128 + sl * 16]);
      }
#pragma unroll
      for (int m = 0; m < 4; ++m)
#pragma unroll
        for (int n = 0; n < 4; ++n)
          acc[m][n] = __builtin_amdgcn_mfma_i32_16x16x64_i8(af[m], bf[n], acc[m][n], 0, 0, 0);
    }

    __builtin_amdgcn_sched_barrier(0);
    __builtin_amdgcn_s_barrier();             // buf cur consumed by all waves
    if (t + 2 < nT) STAGE(cur, t + 2);

    // group close (g == t, GS == TK): accf += s[col] * float(acc); acc = 0
    float s[4];
#pragma unroll
    for (int n = 0; n < 4; ++n)
      s[n] = sS[t * 128 + wc * 64 + n * 16 + l15];
#pragma unroll
    for (int m = 0; m < 4; ++m)
#pragma unroll
      for (int n = 0; n < 4; ++n) {
        accf[m][n] += s[n] * __builtin_convertvector(acc[m][n], f32x4);
        acc[m][n] = (i32x4)0;
      }
    __builtin_amdgcn_sched_barrier(0);
  }

  // epilogue: D row = l4*4 + r, col = l15 (verified, dtype-independent)
#pragma unroll
  for (int n = 0; n < 4; ++n) {
    const int col = tileN + wc * 64 + n * 16 + l15;
    const float bv = bias[col];
#pragma unroll
    for (int m = 0; m < 4; ++m) {
      const int rbase = tileM + wr * 64 + m * 16 + l4 * 4;
#pragma unroll
      for (int r = 0; r < 4; ++r)
        out[(size_t)(rbase + r) * N + col] = accf[m][n][r] + bv;
    }
  }
}

// ======================= last-resort fallback (no ws) =======================
#define FBM 128
#define FBN 128
#define FBK 64
__global__ __launch_bounds__(256)
void gptq_gemm_fb(const float* __restrict__ x, const int* __restrict__ qw,
                  const float* __restrict__ scales, const float* __restrict__ bias,
                  float* __restrict__ out, int M, int N, int K, int NG, int GS) {
  __shared__ __bf16 lds_a[FBM * FBK];
  __shared__ __bf16 lds_b[FBN * FBK];
  const int tid = threadIdx.x, lane = tid & 63, wave = tid >> 6;
  const int wr = wave >> 1, wc = wave & 1;
  const int tileM = blockIdx.y * FBM, tileN = blockIdx.x * FBN;
  const int l15 = lane & 15, l4 = lane >> 4;
  f32x4 acc[4][4];
#pragma unroll
  for (int m = 0; m < 4; ++m)
#pragma unroll
    for (int n = 0; n < 4; ++n) acc[m][n] = (f32x4)0.0f;
  for (int k0 = 0; k0 < K; k0 += FBK) {
    const int g = k0 / GS;
#pragma unroll
    for (int i = 0; i < 4; ++i) {
      int u = i * 256 + tid, row = u >> 3, c8 = u & 7;
      const f32x4* src = reinterpret_cast<const f32x4*>(x + (size_t)(tileM + row) * K + k0 + c8 * 8);
      f32x4 v0 = src[0], v1 = src[1];
      bf16x8 w;
      w[0]=(__bf16)v0[0]; w[1]=(__bf16)v0[1]; w[2]=(__bf16)v0[2]; w[3]=(__bf16)v0[3];
      w[4]=(__bf16)v1[0]; w[5]=(__bf16)v1[1]; w[6]=(__bf16)v1[2]; w[7]=(__bf16)v1[3];
      int slot = c8 ^ (row & 7);
      *reinterpret_cast<bf16x8*>(&lds_a[row * FBK + slot * 8]) = w;
    }
#pragma unroll
    for (int i = 0; i < 4; ++i) {
      int u = i * 256 + tid, row = u >> 3, c8 = u & 7;
      int gn = tileN + row;
      const i32x4* src = reinterpret_cast<const i32x4*>(qw + (size_t)gn * K + k0 + c8 * 8);
      i32x4 q0 = src[0], q1 = src[1];
      float s = scales[gn * NG + g];
      bf16x8 w;
      w[0]=(__bf16)((float)q0[0]*s); w[1]=(__bf16)((float)q0[1]*s);
      w[2]=(__bf16)((float)q0[2]*s); w[3]=(__bf16)((float)q0[3]*s);
      w[4]=(__bf16)((float)q1[0]*s); w[5]=(__bf16)((float)q1[1]*s);
      w[6]=(__bf16)((float)q1[2]*s); w[7]=(__bf16)((float)q1[3]*s);
      int slot = c8 ^ (row & 7);
      *reinterpret_cast<bf16x8*>(&lds_b[row * FBK + slot * 8]) = w;
    }
    __syncthreads();
#pragma unroll
    for (int kk = 0; kk < FBK; kk += 32) {
      bf16x8 af[4], bfr[4];
#pragma unroll
      for (int m = 0; m < 4; ++m) {
        int row = wr * 64 + m * 16 + l15, slot = ((kk >> 3) + l4) ^ (row & 7);
        af[m] = *reinterpret_cast<const bf16x8*>(&lds_a[row * FBK + slot * 8]);
      }
#pragma unroll
      for (int n = 0; n < 4; ++n) {
        int row = wc * 64 + n * 16 + l15, slot = ((kk >> 3) + l4) ^ (row & 7);
        bfr[n] = *reinterpret_cast<const bf16x8*>(&lds_b[row * FBK + slot * 8]);
      }
#pragma unroll
      for (int m = 0; m < 4; ++m)
#pragma unroll
        for (int n = 0; n < 4; ++n)
          acc[m][n] = __builtin_amdgcn_mfma_f32_16x16x32_bf16(af[m], bfr[n], acc[m][n], 0, 0, 0);
    }
    __syncthreads();
  }
#pragma unroll
  for (int n = 0; n < 4; ++n) {
    int coln = tileN + wc * 64 + n * 16 + l15;
    float bv = bias[coln];
#pragma unroll
    for (int m = 0; m < 4; ++m) {
      int rbase = tileM + wr * 64 + m * 16 + l4 * 4;
#pragma unroll
      for (int r = 0; r < 4; ++r)
        out[(size_t)(rbase + r) * N + coln] = acc[m][n][r] + bv;
    }
  }
}

extern "C" void kernel_launch(void* const* d_in, const int* in_sizes, int n_in,
                              void* d_out, int out_size, void* d_ws, size_t ws_size,
                              hipStream_t stream) {
  const float* x      = (const float*)d_in[0];
  const int*   qw     = (const int*)d_in[1];
  const float* scales = (const float*)d_in[2];
  const float* bias   = (const float*)d_in[3];
  float*       out    = (float*)d_out;

  const int OUT = in_sizes[3];            // 11008
  const int IN  = in_sizes[1] / OUT;      // 4096
  const int M   = in_sizes[0] / IN;       // 512
  const int NG  = in_sizes[2] / OUT;      // 32
  const int GS  = IN / NG;                // 128

  const size_t needB = (size_t)OUT * IN;              // 45.1 MB int8
  const size_t needA = (size_t)M * IN;                // 2.1 MB int8
  const int nT = IN / TK;                             // 32

  const bool ok_i8 =
      (ws_size >= needB + needA) && (M % TM == 0) && (OUT % TN == 0) &&
      (IN % TK == 0) && (GS == TK) && (NG == nT) && (NG <= 32) && (nT >= 4) &&
      (OUT % PROWS == 0) && (IN % 16 == 0);

  if (ok_i8) {
    int8_t* wsB = (int8_t*)d_ws;
    int8_t* wsA = (int8_t*)d_ws + needB;
    const int nbB = OUT / PROWS;          // 1376
    const int bands = M / 128;            // 4
    const int nbA = (bands * nT * 1024) / 256;   // 512 units/tile -> 128 blocks
    prepass_i8<<<nbB + nbA, 256, 0, stream>>>(qw, x, wsB, wsA, IN, nT, nbB);
    const int gx = OUT / TN;              // 86
    const int gy = M / TM;                // 4
    gemm_i8<<<gx * gy, 256, 0, stream>>>(wsA, wsB, scales, bias, out, OUT, IN, NG, gy);
  } else {
    dim3 grid(OUT / FBN, M / FBM);
    gptq_gemm_fb<<<grid, 256, 0, stream>>>(x, qw, scales, bias, out, M, OUT, IN, NG, GS);
  }
}